// Round 9
// baseline (12224.162 us; speedup 1.0000x reference)
//
#include <hip/hip_runtime.h>
#include <math.h>

typedef _Float16 f16_t;
typedef _Float16 half8 __attribute__((ext_vector_type(8)));
typedef float f32x4 __attribute__((ext_vector_type(4)));

#define LDK 384
#define NMP 1664  // padded m' dim (2*800 -> 13*128)

struct Params {
  const float *x_seq, *t_x, *t_y, *G;
  const float *Wraw[8], *bia[8];  // idx = dec*4 + layer*2 + cand
  const float *mW1, *mb1, *mW2, *mb2, *mem, *Wa, *fc, *projW, *projb;
  float* dout;
  float *h0, *h1, *txe, *tye, *hidb, *Wat;
  f16_t *Uh, *Xp, *Atp, *T2h;
  f16_t *wh[8], *wl[8];
};

__device__ __forceinline__ float sigm(float x) { return 1.0f / (1.0f + expf(-x)); }

// bijective XCD swizzle (m204): chunk consecutive linear ids per XCD
__device__ __forceinline__ int xcd_swz(int orig, int nwg) {
  int q = nwg >> 3, r = nwg & 7, xcd = orig & 7, j = orig >> 3;
  return (xcd < r ? xcd * (q + 1) : r * (q + 1) + (xcd - r) * q) + j;
}

// ================= prologue =================

__global__ void __launch_bounds__(256) k_pre0(Params p) {
  int nt = gridDim.x * blockDim.x, id = blockIdx.x * blockDim.x + threadIdx.x;
  float4 z = {0.f, 0.f, 0.f, 0.f};
  for (int i = id; i < 64 * 64 * 200; i += nt) { ((float4*)p.h0)[i] = z; ((float4*)p.h1)[i] = z; }
  for (int w = 0; w < 8; ++w) {
    int layer = (w >> 1) & 1, cand = w & 1;
    int P = layer ? 128 : 68, NC = cand ? 64 : 128, Kp = layer ? 384 : 224;
    const float* W = p.Wraw[w];
    f16_t* Wth = p.wh[w];
    f16_t* Wtl = p.wl[w];
    for (int idx = id; idx < Kp * NC; idx += nt) {
      int i = idx / NC, c = idx - i * NC;
      float v = 0.f;
      if (i < 3 * P) {
        int k = i / P, pp = i - k * P;
        if (k == 0)
          v = W[(size_t)pp * NC + c] + 0.05f * (W[(size_t)(P + pp) * NC + c] + W[(size_t)(2 * P + pp) * NC + c]);
        else
          v = 0.95f * W[(size_t)i * NC + c];
      }
      f16_t h = (f16_t)v;
      Wth[(size_t)c * Kp + i] = h;
      Wtl[(size_t)c * Kp + i] = (f16_t)((v - (float)h) * 2048.0f);
    }
  }
  for (int idx = id; idx < 15360; idx += nt) {
    int half = idx / 7680, rem = idx - half * 7680;
    int r = rem / 10, j = rem - r * 10;
    const float* tin = half ? p.t_y : p.t_x;
    float a = p.mb1[j];
    for (int k = 0; k < 60; ++k) a += tin[(size_t)r * 60 + k] * p.mW1[k * 10 + j];
    p.hidb[idx] = a;
  }
  // Wat[(c*800+n)*8+d] = Wa[(n*64+c)*8+d]
  for (int idx = id; idx < 409600; idx += nt) {
    int c = idx / 6400, r2 = idx - c * 6400;
    int n = r2 >> 3, d = r2 & 7;
    p.Wat[idx] = p.Wa[((size_t)n * 64 + c) * 8 + d];
  }
}

// T2h = 2*G@G - I (f16), plus mlp_out
__global__ void __launch_bounds__(256) k_pre1(Params p) {
  __shared__ float As[16 * 68];
  __shared__ float Bs[16 * 68];
  int tid = threadIdx.x, tx = tid & 15, ty = tid >> 4;
  const float* A = p.G;
  for (int tile = blockIdx.x; tile < 169; tile += gridDim.x) {
    int bx = tile % 13, by = tile / 13;
    int rowBase = by * 64, colBase = bx * 64;
    float acc[4][4] = {};
    for (int k0 = 0; k0 < 800; k0 += 16) {
      __syncthreads();
      for (int e = tid; e < 1024; e += 256) {
        int r = e >> 4, c = e & 15;
        int gr = rowBase + r;
        As[c * 68 + r] = (gr < 800) ? A[gr * 800 + k0 + c] : 0.f;
      }
      for (int e = tid; e < 1024; e += 256) {
        int r = e >> 6, c = e & 63;
        int gc = colBase + c;
        Bs[r * 68 + c] = (gc < 800) ? A[(k0 + r) * 800 + gc] : 0.f;
      }
      __syncthreads();
#pragma unroll
      for (int kk = 0; kk < 16; ++kk) {
        float4 a4 = *(const float4*)&As[kk * 68 + ty * 4];
        float4 b4 = *(const float4*)&Bs[kk * 68 + tx * 4];
        float av[4] = {a4.x, a4.y, a4.z, a4.w};
        float bv[4] = {b4.x, b4.y, b4.z, b4.w};
#pragma unroll
        for (int i = 0; i < 4; ++i)
#pragma unroll
          for (int j = 0; j < 4; ++j) acc[i][j] += av[i] * bv[j];
      }
    }
#pragma unroll
    for (int i = 0; i < 4; ++i) {
      int m = rowBase + ty * 4 + i;
      if (m >= 800) continue;
#pragma unroll
      for (int j = 0; j < 4; ++j) {
        int n = colBase + tx * 4 + j;
        if (n < 800) p.T2h[(size_t)m * 800 + n] = (f16_t)(2.f * acc[i][j] - (m == n ? 1.f : 0.f));
      }
    }
  }
  int nt = gridDim.x * blockDim.x, id = blockIdx.x * blockDim.x + threadIdx.x;
  for (int idx = id; idx < 2 * 768 * 1600; idx += nt) {
    int half = idx / (768 * 1600), rem = idx - half * (768 * 1600);
    int r = rem / 1600, o = rem - r * 1600;
    const float* hid = p.hidb + half * 7680;
    float* emb = half ? p.tye : p.txe;
    float a = p.mb2[o];
#pragma unroll
    for (int k = 0; k < 10; ++k) a += hid[r * 10 + k] * p.mW2[k * 1600 + o];
    emb[rem] = a;
  }
}

// Atp[kp][m'][kk] = B[k][m']; B = [G | T2]  (A1^T = G, A2^T = T2)
__global__ void __launch_bounds__(256) k_pre2(Params p) {
  int nt = gridDim.x * blockDim.x, id = blockIdx.x * blockDim.x + threadIdx.x;
  for (int idx = id; idx < 25 * NMP * 32; idx += nt) {
    int kp = idx / (NMP * 32), r = idx - kp * (NMP * 32);
    int mp = r >> 5, kk = r & 31;
    int k = kp * 32 + kk;
    f16_t v;
    if (mp < 800) v = (f16_t)p.G[(size_t)k * 800 + mp];
    else if (mp < 1600) v = p.T2h[(size_t)k * 800 + (mp - 800)];
    else v = (f16_t)0.f;
    p.Atp[idx] = v;
  }
}

// ================= packs: materialize plane0 into Xp only =================

__global__ void __launch_bounds__(256) g_pack0(Params p, int dec, int t) {
  int r = blockIdx.x;
  int b = r / 68, c = r - b * 68;
  const float* hsrc = p.h0 + (size_t)(b * 64 + (c >= 4 ? c - 4 : 0)) * 800;
  f16_t* z2 = p.Xp + ((size_t)b * LDK + c) * 800;
  for (int n = threadIdx.x; n < 800; n += 256) {
    float v;
    if (c >= 4) v = hsrc[n];
    else if (c < 2) {
      if (dec) v = (t == 0) ? 0.f : p.dout[((size_t)(b * 12 + t - 1) * 800 + n) * 2 + c];
      else v = p.x_seq[((size_t)(b * 12 + t) * 800 + n) * 2 + c];
    } else {
      const float* e = dec ? p.tye : p.txe;
      v = e[(size_t)(b * 12 + t) * 1600 + n * 2 + (c - 2)];
    }
    z2[n] = (f16_t)v;
  }
}

__global__ void __launch_bounds__(256) g_pack1(Params p) {
  int r = blockIdx.x;
  int b = r >> 7, c = r & 127;
  const float* hs = (c < 64) ? p.h0 + (size_t)(b * 64 + c) * 800 : p.h1 + (size_t)(b * 64 + c - 64) * 800;
  f16_t* z2 = p.Xp + ((size_t)b * LDK + c) * 800;
  for (int n = threadIdx.x; n < 800; n += 256) z2[n] = (f16_t)hs[n];
}

// ================= graph GEMM: D[r][m'] = sum_k X[rowmap(r)][k] * B[k][m'] =================
// block 256 rows x 128 m', 4 waves 2x2, wave 128x64. A read from Xp via row mapping.
template <int PM>
__global__ void __launch_bounds__(256, 2) g_gconv(Params p, int rowOff, int P, int cOff) {
  int nwg = gridDim.x * gridDim.y;
  int orig = blockIdx.y * gridDim.x + blockIdx.x;
  int swz = xcd_swz(orig, nwg);
  int mBase = (swz % 13) * 128;
  int rBase = (swz / 13) * 256;

  __shared__ f16_t AS[256 * 40];
  __shared__ f16_t BS[128 * 40];
  int tid = threadIdx.x, lane = tid & 63, wid = tid >> 6;
  int wm = wid >> 1, wn = wid & 1;
  int lrow = lane & 15, lgrp = lane >> 4;

  int ar = rBase + tid;
  int ab = ar / PM, ac = ar - ab * PM;
  const f16_t* Asrc = p.Xp + ((size_t)ab * LDK + rowOff + ac) * 800;
  int bmp = tid >> 1, bhalf = tid & 1;
  const f16_t* Bsrc = p.Atp + (size_t)(mBase + bmp) * 32 + bhalf * 16;

  uint4 rA[4], rB[2];
  auto pf = [&](int ks) {
    const f16_t* a = Asrc + ks * 32;
    rA[0] = *(const uint4*)a;
    rA[1] = *(const uint4*)(a + 8);
    rA[2] = *(const uint4*)(a + 16);
    rA[3] = *(const uint4*)(a + 24);
    const f16_t* bq = Bsrc + (size_t)ks * (NMP * 32);
    rB[0] = *(const uint4*)bq;
    rB[1] = *(const uint4*)(bq + 8);
  };

  f32x4 acc[8][4];
#pragma unroll
  for (int i = 0; i < 8; ++i)
#pragma unroll
    for (int j = 0; j < 4; ++j) acc[i][j] = (f32x4){0.f, 0.f, 0.f, 0.f};

  pf(0);
  for (int ks = 0; ks < 25; ++ks) {
    if (ks) __syncthreads();
    int sa = tid * 40;
    *(uint4*)(AS + sa) = rA[0];
    *(uint4*)(AS + sa + 8) = rA[1];
    *(uint4*)(AS + sa + 16) = rA[2];
    *(uint4*)(AS + sa + 24) = rA[3];
    int sb = bmp * 40 + bhalf * 16;
    *(uint4*)(BS + sb) = rB[0];
    *(uint4*)(BS + sb + 8) = rB[1];
    if (ks + 1 < 25) pf(ks + 1);
    __syncthreads();
    half8 fa[8], fb[4];
#pragma unroll
    for (int mt = 0; mt < 8; ++mt) fa[mt] = *(const half8*)(AS + (wm * 128 + mt * 16 + lrow) * 40 + lgrp * 8);
#pragma unroll
    for (int nt = 0; nt < 4; ++nt) fb[nt] = *(const half8*)(BS + (wn * 64 + nt * 16 + lrow) * 40 + lgrp * 8);
#pragma unroll
    for (int mt = 0; mt < 8; ++mt)
#pragma unroll
      for (int nt = 0; nt < 4; ++nt) acc[mt][nt] = __builtin_amdgcn_mfma_f32_16x16x32_f16(fa[mt], fb[nt], acc[mt][nt], 0, 0, 0);
  }

#pragma unroll
  for (int mt = 0; mt < 8; ++mt)
#pragma unroll
    for (int nt = 0; nt < 4; ++nt) {
      int mp = mBase + wn * 64 + nt * 16 + lrow;
      if (mp >= 1600) continue;
      int pl2 = (mp >= 800);
      int m = mp - (pl2 ? 800 : 0);
      int pbase = (pl2 ? 2 : 1) * P + cOff;
#pragma unroll
      for (int j = 0; j < 4; ++j) {
        int r = rBase + wm * 128 + mt * 16 + lgrp * 4 + j;
        int b = r / PM, c = r - b * PM;
        p.Xp[((size_t)b * LDK + pbase + c) * 800 + m] = (f16_t)acc[mt][nt][j];
      }
    }
}

// ================= proj (transposed): D[c_out][n] = sum_k Wfold[k][c_out] * X[b][k][n] =================
template <int NC, int MODE>
__global__ void __launch_bounds__(256, 3) g_proj(Params p, int widx, int K3, int Pin, float* hcur) {
  const int NKT = (K3 + 31) >> 5;
  const int Kp = NKT * 32;
  const int MW = NC / 4;
  const int NMF = MW / 16;
  const int SL = (NC * 4) / 256;
  __shared__ f16_t WhS[NC * 40];
  __shared__ f16_t WlS[NC * 40];
  __shared__ f16_t XS[64 * 40];
  int tid = threadIdx.x, lane = tid & 63, wid = tid >> 6;
  int lrow = lane & 15, lgrp = lane >> 4;
  int nwg = gridDim.x * gridDim.y;
  int orig = blockIdx.y * gridDim.x + blockIdx.x;
  int swz = xcd_swz(orig, nwg);
  int b = swz / 13, nBase = (swz % 13) * 64;
  const f16_t* __restrict__ Wth = p.wh[widx];
  const f16_t* __restrict__ Wtl = p.wl[widx];
  const float* bias = p.bia[widx];
  const f16_t* Xb = p.Xp + (size_t)b * LDK * 800;

  int k2 = tid >> 3, ng = tid & 7;
  bool xact = tid < 128;
  bool nval = (nBase + ng * 8 + 7) < 800;

  uint4 rwh[SL], rwl[SL];
  half8 rx0, rx1;
  auto pfW = [&](int ks) {
#pragma unroll
    for (int s = 0; s < SL; ++s) {
      int slot = tid + s * 256;
      int row = slot >> 2, q = slot & 3;
      size_t g = (size_t)row * Kp + ks * 32 + q * 8;
      rwh[s] = *(const uint4*)(Wth + g);
      rwl[s] = *(const uint4*)(Wtl + g);
    }
  };
  auto pfX = [&](int ks) {
    if (!xact) return;
    int k = ks * 32 + 2 * k2;
    const f16_t* xs = Xb + (size_t)k * 800 + nBase + ng * 8;
    half8 zz = {};
    rx0 = (nval && k < K3) ? *(const half8*)xs : zz;
    rx1 = (nval && k + 1 < K3) ? *(const half8*)(xs + 800) : zz;
  };

  f32x4 aM[NMF][4], aC[NMF][4];
#pragma unroll
  for (int i = 0; i < NMF; ++i)
#pragma unroll
    for (int j = 0; j < 4; ++j) {
      aM[i][j] = (f32x4){0.f, 0.f, 0.f, 0.f};
      aC[i][j] = (f32x4){0.f, 0.f, 0.f, 0.f};
    }

  pfW(0);
  pfX(0);
  for (int ks = 0; ks < NKT; ++ks) {
    if (ks) __syncthreads();
#pragma unroll
    for (int s = 0; s < SL; ++s) {
      int slot = tid + s * 256;
      int row = slot >> 2, q = slot & 3;
      *(uint4*)(WhS + row * 40 + q * 8) = rwh[s];
      *(uint4*)(WlS + row * 40 + q * 8) = rwl[s];
    }
    if (xact) {
#pragma unroll
      for (int i = 0; i < 8; ++i) {
        union { f16_t h[2]; unsigned u; } pk;
        pk.h[0] = rx0[i];
        pk.h[1] = rx1[i];
        *(unsigned*)&XS[(ng * 8 + i) * 40 + 2 * k2] = pk.u;
      }
    }
    if (ks + 1 < NKT) { pfW(ks + 1); pfX(ks + 1); }
    __syncthreads();
    half8 fx[4];
#pragma unroll
    for (int nt = 0; nt < 4; ++nt) fx[nt] = *(const half8*)(XS + (nt * 16 + lrow) * 40 + lgrp * 8);
#pragma unroll
    for (int mf = 0; mf < NMF; ++mf) {
      int row = wid * MW + mf * 16 + lrow;
      half8 wh8 = *(const half8*)(WhS + row * 40 + lgrp * 8);
      half8 wl8 = *(const half8*)(WlS + row * 40 + lgrp * 8);
#pragma unroll
      for (int nt = 0; nt < 4; ++nt) {
        aM[mf][nt] = __builtin_amdgcn_mfma_f32_16x16x32_f16(wh8, fx[nt], aM[mf][nt], 0, 0, 0);
        aC[mf][nt] = __builtin_amdgcn_mfma_f32_16x16x32_f16(wl8, fx[nt], aC[mf][nt], 0, 0, 0);
      }
    }
  }

#pragma unroll
  for (int mf = 0; mf < NMF; ++mf)
#pragma unroll
    for (int nt = 0; nt < 4; ++nt) {
      int n = nBase + nt * 16 + lrow;
      if (n >= 800) continue;
#pragma unroll
      for (int j = 0; j < 4; ++j) {
        int co = wid * MW + mf * 16 + lgrp * 4 + j;
        float v = aM[mf][nt][j] + aC[mf][nt][j] * (1.0f / 2048.0f) + bias[co];
        if (MODE == 0) {
          if (co < 64) {
            p.Uh[(size_t)(b * 64 + co) * 800 + n] = (f16_t)sigm(v);
          } else {
            int jj = co - 64;
            float hv = hcur[(size_t)(b * 64 + jj) * 800 + n];
            p.Xp[((size_t)b * LDK + Pin + jj) * 800 + n] = (f16_t)(sigm(v) * hv);
          }
        } else {
          float u = (float)p.Uh[(size_t)(b * 64 + co) * 800 + n];
          float hv = hcur[(size_t)(b * 64 + co) * 800 + n];
          hcur[(size_t)(b * 64 + co) * 800 + n] = (1.f - u) * hv + u * tanhf(v);
        }
      }
    }
}

// ================= fused memory-attention + output projection (1 block per batch) =================

__global__ void __launch_bounds__(256) k_att(Params p, int t) {
  __shared__ float red[256][8];
  __shared__ float attv[8];
  int b = blockIdx.x, tid = threadIdx.x;
  float acc[8] = {};
  const float* hrow = p.h1 + (size_t)b * 51200;
  for (int i = tid; i < 51200; i += 256) {
    float hv = hrow[i];
    const float* wr = p.Wat + (size_t)i * 8;
#pragma unroll
    for (int j = 0; j < 8; ++j) acc[j] += hv * wr[j];
  }
#pragma unroll
  for (int j = 0; j < 8; ++j) red[tid][j] = acc[j];
  __syncthreads();
  for (int s = 128; s > 0; s >>= 1) {
    if (tid < s) {
#pragma unroll
      for (int j = 0; j < 8; ++j) red[tid][j] += red[tid + s][j];
    }
    __syncthreads();
  }
  if (tid == 0) {
    float q[8];
#pragma unroll
    for (int j = 0; j < 8; ++j) q[j] = red[0][j];
    float sco[4], mx = -1e30f;
#pragma unroll
    for (int m = 0; m < 4; ++m) {
      float s = 0.f;
#pragma unroll
      for (int d = 0; d < 8; ++d) s += q[d] * p.mem[m * 8 + d];
      sco[m] = s;
      mx = fmaxf(mx, s);
    }
    float se = 0.f;
#pragma unroll
    for (int m = 0; m < 4; ++m) { sco[m] = expf(sco[m] - mx); se += sco[m]; }
#pragma unroll
    for (int d = 0; d < 8; ++d) {
      float av = 0.f;
#pragma unroll
      for (int m = 0; m < 4; ++m) av += (sco[m] / se) * p.mem[m * 8 + d];
      attv[d] = av;
    }
  }
  __syncthreads();
  for (int n = tid; n < 800; n += 256) {
    float attm[8];
#pragma unroll
    for (int d = 0; d < 8; ++d) {
      float s = 0.f;
#pragma unroll
      for (int m = 0; m < 8; ++m) s += attv[m] * p.fc[(size_t)m * 6400 + n * 8 + d];
      attm[d] = s;
    }
    float o0 = p.projb[0], o1 = p.projb[1];
    const float* hb = p.h1 + (size_t)b * 51200 + n;
#pragma unroll 16
    for (int j = 0; j < 64; ++j) {
      float hv = hb[(size_t)j * 800];
      o0 += hv * p.projW[j * 2 + 0];
      o1 += hv * p.projW[j * 2 + 1];
    }
#pragma unroll
    for (int d = 0; d < 8; ++d) {
      o0 += attm[d] * p.projW[(64 + d) * 2 + 0];
      o1 += attm[d] * p.projW[(64 + d) * 2 + 1];
    }
    size_t base = ((size_t)(b * 12 + t) * 800 + n) * 2;
    p.dout[base + 0] = fmaxf(o0, 0.f);
    p.dout[base + 1] = fmaxf(o1, 0.f);
  }
}

// ================= host =================

extern "C" void kernel_launch(void* const* d_in, const int* in_sizes, int n_in,
                              void* d_out, int out_size, void* d_ws, size_t ws_size,
                              hipStream_t stream) {
  Params P;
  P.x_seq = (const float*)d_in[0];
  P.t_x = (const float*)d_in[1];
  P.t_y = (const float*)d_in[2];
  P.G = (const float*)d_in[3];
  P.Wraw[0] = (const float*)d_in[4];  P.bia[0] = (const float*)d_in[5];
  P.Wraw[1] = (const float*)d_in[6];  P.bia[1] = (const float*)d_in[7];
  P.Wraw[2] = (const float*)d_in[8];  P.bia[2] = (const float*)d_in[9];
  P.Wraw[3] = (const float*)d_in[10]; P.bia[3] = (const float*)d_in[11];
  P.Wraw[4] = (const float*)d_in[12]; P.bia[4] = (const float*)d_in[13];
  P.Wraw[5] = (const float*)d_in[14]; P.bia[5] = (const float*)d_in[15];
  P.Wraw[6] = (const float*)d_in[16]; P.bia[6] = (const float*)d_in[17];
  P.Wraw[7] = (const float*)d_in[18]; P.bia[7] = (const float*)d_in[19];
  P.mW1 = (const float*)d_in[20];
  P.mb1 = (const float*)d_in[21];
  P.mW2 = (const float*)d_in[22];
  P.mb2 = (const float*)d_in[23];
  P.mem = (const float*)d_in[24];
  P.Wa = (const float*)d_in[25];
  P.fc = (const float*)d_in[26];
  P.projW = (const float*)d_in[27];
  P.projb = (const float*)d_in[28];
  P.dout = (float*)d_out;

  float* ws = (float*)d_ws;
  size_t off = 0;
  auto alloc = [&](size_t nel) { float* q = ws + off; off += (nel + 3) & ~(size_t)3; return q; };
  P.T2h = (f16_t*)alloc(320000);
  P.Atp = (f16_t*)alloc((size_t)25 * NMP * 32 / 2);
  P.Xp = (f16_t*)alloc((size_t)64 * LDK * 800 / 2);
  P.Uh = (f16_t*)alloc((size_t)4096 * 800 / 2);
  P.h0 = alloc((size_t)4096 * 800);
  P.h1 = alloc((size_t)4096 * 800);
  P.txe = alloc((size_t)768 * 1600);
  P.tye = alloc((size_t)768 * 1600);
  P.hidb = alloc(15360);
  P.Wat = alloc(409600);
  const int kpnc[8] = {224 * 128, 224 * 64, 384 * 128, 384 * 64, 224 * 128, 224 * 64, 384 * 128, 384 * 64};
  for (int w = 0; w < 8; ++w) {
    P.wh[w] = (f16_t*)alloc((kpnc[w] + 1) / 2);
    P.wl[w] = (f16_t*)alloc((kpnc[w] + 1) / 2);
  }

  k_pre0<<<512, 256, 0, stream>>>(P);
  k_pre1<<<512, 256, 0, stream>>>(P);
  k_pre2<<<512, 256, 0, stream>>>(P);

  auto cell = [&](int dec, int t) {
    // ---- layer 0 (P=68, Pin=4, K3=204) ----
    g_pack0<<<4352, 256, 0, stream>>>(P, dec, t);
    g_gconv<68><<<dim3(13, 17), 256, 0, stream>>>(P, 0, 68, 0);
    g_proj<128, 0><<<dim3(13, 64), 256, 0, stream>>>(P, dec * 4 + 0, 204, 4, P.h0);
    g_gconv<64><<<dim3(13, 16), 256, 0, stream>>>(P, 4, 68, 4);
    g_proj<64, 1><<<dim3(13, 64), 256, 0, stream>>>(P, dec * 4 + 1, 204, 4, P.h0);
    // ---- layer 1 (P=128, Pin=64, K3=384) ----
    g_pack1<<<8192, 256, 0, stream>>>(P);
    g_gconv<128><<<dim3(13, 32), 256, 0, stream>>>(P, 0, 128, 0);
    g_proj<128, 0><<<dim3(13, 64), 256, 0, stream>>>(P, dec * 4 + 2, 384, 64, P.h1);
    g_gconv<64><<<dim3(13, 16), 256, 0, stream>>>(P, 64, 128, 64);
    g_proj<64, 1><<<dim3(13, 64), 256, 0, stream>>>(P, dec * 4 + 3, 384, 64, P.h1);
  };

  for (int t = 0; t < 12; ++t) cell(0, t);
  for (int t = 0; t < 12; ++t) {
    cell(1, t);
    k_att<<<64, 256, 0, stream>>>(P, t);
  }
}